// Round 3
// baseline (149.242 us; speedup 1.0000x reference)
//
#include <hip/hip_runtime.h>
#include <math.h>

#define N_NODES 131072
#define H 256
#define HH 128
#define B_GRAPHS 512

typedef __attribute__((ext_vector_type(8))) short bfrag8;
typedef __attribute__((ext_vector_type(16))) float f32x16;

__device__ __forceinline__ float bfhi(float v) {
  return __builtin_bit_cast(float, __builtin_bit_cast(unsigned, v) & 0xFFFF0000u);
}

// ---------------- K0: pre-split W1 into 3 bf16 planes, transposed [s][col][k] ----------------
__global__ void k_prep_w1(const float* __restrict__ W1, ushort* __restrict__ W1s) {
  const int idx = blockIdx.x * 256 + threadIdx.x;  // 32768 = 256*128
  const int k = idx >> 7, c = idx & 127;
  const float v = W1[idx];
  const float r = v - bfhi(v);
  const float r2 = r - bfhi(r);
  W1s[0 * 32768 + c * 256 + k] = (ushort)(__builtin_bit_cast(unsigned, v) >> 16);
  W1s[1 * 32768 + c * 256 + k] = (ushort)(__builtin_bit_cast(unsigned, r) >> 16);
  W1s[2 * 32768 + c * 256 + k] = (ushort)(__builtin_bit_cast(unsigned, r2) >> 16);
}

// ---------------- K1: segment bounds (batch is sorted) ----------------
__global__ void k_seg_bounds(const int* __restrict__ batch, int* __restrict__ seg_start,
                             int N, int B) {
  int b = blockIdx.x * blockDim.x + threadIdx.x;
  if (b > B) return;
  int lo = 0, hi = N;
  while (lo < hi) {
    int mid = (lo + hi) >> 1;
    if (batch[mid] < b) lo = mid + 1; else hi = mid;
  }
  seg_start[b] = lo;
}

// ---------------- K2: score MLP via split-bf16 MFMA, barrier-free main loop ----------------
#define PROD(sa, sb)                                                                        \
  do {                                                                                      \
    acc[0][0] = __builtin_amdgcn_mfma_f32_32x32x16_bf16(af[sa][0], bcur[sb][0], acc[0][0],  \
                                                        0, 0, 0);                           \
    acc[0][1] = __builtin_amdgcn_mfma_f32_32x32x16_bf16(af[sa][0], bcur[sb][1], acc[0][1],  \
                                                        0, 0, 0);                           \
    acc[1][0] = __builtin_amdgcn_mfma_f32_32x32x16_bf16(af[sa][1], bcur[sb][0], acc[1][0],  \
                                                        0, 0, 0);                           \
    acc[1][1] = __builtin_amdgcn_mfma_f32_32x32x16_bf16(af[sa][1], bcur[sb][1], acc[1][1],  \
                                                        0, 0, 0);                           \
  } while (0)

__device__ __forceinline__ void split8(const float4 v0, const float4 v1,
                                       bfrag8& p1, bfrag8& p2, bfrag8& p3) {
  const float vals[8] = {v0.x, v0.y, v0.z, v0.w, v1.x, v1.y, v1.z, v1.w};
#pragma unroll
  for (int e = 0; e < 8; ++e) {
    const float v = vals[e];
    const float r = v - bfhi(v);
    const float r2 = r - bfhi(r);
    p1[e] = (short)(__builtin_bit_cast(unsigned, v) >> 16);
    p2[e] = (short)(__builtin_bit_cast(unsigned, r) >> 16);
    p3[e] = (short)(__builtin_bit_cast(unsigned, r2) >> 16);
  }
}

__global__ __launch_bounds__(256, 2) void k_score_mfma(
    const float* __restrict__ x, const ushort* __restrict__ W1s,
    const float* __restrict__ b1, const float* __restrict__ W2,
    const float* __restrict__ b2, float* __restrict__ s_out) {
  __shared__ float part[128 * 64];  // 32 KB, epilogue only
  const int t = threadIdx.x;
  const int lane = t & 63;
  const int w = t >> 6;
  const int wr = w >> 1, wc = w & 1;
  const int nl = lane & 31, g = lane >> 5;
  const int node0 = blockIdx.x * 128;

  const float* xA0 = x + (size_t)(node0 + wr * 64 + nl) * H + g * 8;
  const float* xA1 = xA0 + 32 * H;
  const ushort* Wb = W1s + (wc * 64 + nl) * 256 + g * 8;

  const f32x16 zero = (f32x16)0.0f;
  f32x16 acc[2][2];
  acc[0][0] = zero; acc[0][1] = zero; acc[1][0] = zero; acc[1][1] = zero;

  // preload substep 0
  float4 a00 = *(const float4*)(xA0);
  float4 a01 = *(const float4*)(xA0 + 4);
  float4 a10 = *(const float4*)(xA1);
  float4 a11 = *(const float4*)(xA1 + 4);
  bfrag8 bcur[3][2];
#pragma unroll
  for (int s = 0; s < 3; ++s)
#pragma unroll
    for (int j = 0; j < 2; ++j)
      bcur[s][j] = *(const bfrag8*)(Wb + s * 32768 + j * 8192);

#pragma unroll
  for (int ks = 0; ks < 16; ++ks) {
    // prefetch substep ks+1
    float4 n00, n01, n10, n11;
    bfrag8 bnxt[3][2];
    if (ks < 15) {
      const int k0n = (ks + 1) * 16;
      n00 = *(const float4*)(xA0 + k0n);
      n01 = *(const float4*)(xA0 + k0n + 4);
      n10 = *(const float4*)(xA1 + k0n);
      n11 = *(const float4*)(xA1 + k0n + 4);
#pragma unroll
      for (int s = 0; s < 3; ++s)
#pragma unroll
        for (int j = 0; j < 2; ++j)
          bnxt[s][j] = *(const bfrag8*)(Wb + s * 32768 + j * 8192 + k0n);
    }
    // split current A into 3 bf16 planes (in-register)
    bfrag8 af[3][2];
    split8(a00, a01, af[0][0], af[1][0], af[2][0]);
    split8(a10, a11, af[0][1], af[1][1], af[2][1]);
    // 6 split-products
    PROD(0, 0); PROD(1, 0); PROD(0, 1); PROD(1, 1); PROD(2, 0); PROD(0, 2);
    // rotate
    if (ks < 15) {
      a00 = n00; a01 = n01; a10 = n10; a11 = n11;
#pragma unroll
      for (int s = 0; s < 3; ++s)
#pragma unroll
        for (int j = 0; j < 2; ++j) bcur[s][j] = bnxt[s][j];
    }
  }

  // ---- epilogue: layer 2 in fp32 ----
  const int col0 = wc * 64 + nl;
  const float b1v0 = b1[col0], b1v1 = b1[col0 + 32];
  const float w2v0 = W2[col0], w2v1 = W2[col0 + 32];
#pragma unroll
  for (int i = 0; i < 2; ++i) {
#pragma unroll
    for (int r = 0; r < 16; ++r) {
      const int nodeL = wr * 64 + i * 32 + (r & 3) + 8 * (r >> 2) + 4 * g;
      const float h0 = acc[i][0][r] + b1v0;
      const float h1 = acc[i][1][r] + b1v1;
      const float p = fmaxf(h0, 0.f) * w2v0 + fmaxf(h1, 0.f) * w2v1;
      part[nodeL * 64 + wc * 32 + nl] = p;
    }
  }
  __syncthreads();
  if (t < 128) {
    float sv = b2[0];
#pragma unroll 8
    for (int cc = 0; cc < 64; ++cc) {
      const int c2 = (cc + t) & 63;
      sv += part[t * 64 + c2];
    }
    s_out[node0 + t] = sv;
  }
}

// ---------------- K3: fused softmax stats + top-k select + single-pass pools ----------------
__global__ __launch_bounds__(512) void k_pool_fused(const float* __restrict__ x,
                                                    const float* __restrict__ s,
                                                    const int* __restrict__ seg_start,
                                                    float* __restrict__ pooled) {
  const int b = blockIdx.x;
  const int t = threadIdx.x;
  const int start = seg_start[b];
  const int end = seg_start[b + 1];
  const int n = end - start;

  __shared__ float s_lds[1024];
  __shared__ float red[512];
  __shared__ float thr_sh;
  __shared__ int thri_sh;
  __shared__ float r4[8][264];

  const bool fits = (n <= 1024);
  if (fits) {
    for (int i = t; i < n; i += 512) s_lds[i] = s[start + i];
  }
  __syncthreads();
  const float* sseg = fits ? s_lds : (s + start);

  // --- smax
  float m = -INFINITY;
  for (int i = t; i < n; i += 512) m = fmaxf(m, sseg[i]);
  red[t] = m;
  __syncthreads();
  for (int off = 256; off > 0; off >>= 1) {
    if (t < off) red[t] = fmaxf(red[t], red[t + off]);
    __syncthreads();
  }
  const float smax = red[0];
  __syncthreads();
  // --- denom
  float d = 0.f;
  for (int i = t; i < n; i += 512) d += __expf(sseg[i] - smax);
  red[t] = d;
  __syncthreads();
  for (int off = 256; off > 0; off >>= 1) {
    if (t < off) red[t] += red[t + off];
    __syncthreads();
  }
  const float denom = red[0];
  __syncthreads();
  const float inv_denom = (denom > 0.f) ? 1.f / denom : 0.f;

  int k = 0;
  if (n > 0) {
    k = (int)ceilf(0.05f * (float)n);
    if (k < 5) k = 5;
    if (k > 64) k = 64;
    if (k > n) k = n;
  }

  // --- top-k boundary (k-th by s desc, idx asc) via wave-0 threshold descent
  if (t < 64) {
    float pk = INFINITY;
    int pidx = -1;
    for (int r = 0; r < k; ++r) {
      float bk = -INFINITY;
      int bi = 0x7fffffff;
      for (int i = t; i < n; i += 64) {
        const float si = sseg[i];
        const int gi = start + i;
        const bool below = (si < pk) || (si == pk && gi > pidx);
        if (below && (si > bk || (si == bk && gi < bi))) { bk = si; bi = gi; }
      }
#pragma unroll
      for (int off = 32; off > 0; off >>= 1) {
        const float ok = __shfl_xor(bk, off);
        const int oi = __shfl_xor(bi, off);
        if (ok > bk || (ok == bk && oi < bi)) { bk = ok; bi = oi; }
      }
      pk = bk;
      pidx = bi;
    }
    if (t == 0) {
      thr_sh = (k > 0) ? pk : INFINITY;
      thri_sh = (k > 0) ? pidx : -1;
    }
  }
  __syncthreads();
  const float thr = thr_sh;
  const int thri = thri_sh;

  // --- single x stream: mean / attn / max / topk
  const int fq = t & 63;
  const int sub = t >> 6;
  float mean[4] = {0.f, 0.f, 0.f, 0.f};
  float attn[4] = {0.f, 0.f, 0.f, 0.f};
  float tk[4] = {0.f, 0.f, 0.f, 0.f};
  float mx[4] = {-INFINITY, -INFINITY, -INFINITY, -INFINITY};
  for (int i = sub; i < n; i += 8) {
    const float si = sseg[i];
    const float wi = __expf(si - smax);
    const int gi = start + i;
    const bool sel = (si > thr) || (si == thr && gi <= thri);
    const float4 xv = *reinterpret_cast<const float4*>(x + (size_t)gi * H + fq * 4);
    mean[0] += xv.x; mean[1] += xv.y; mean[2] += xv.z; mean[3] += xv.w;
    attn[0] = fmaf(xv.x, wi, attn[0]);
    attn[1] = fmaf(xv.y, wi, attn[1]);
    attn[2] = fmaf(xv.z, wi, attn[2]);
    attn[3] = fmaf(xv.w, wi, attn[3]);
    mx[0] = fmaxf(mx[0], xv.x);
    mx[1] = fmaxf(mx[1], xv.y);
    mx[2] = fmaxf(mx[2], xv.z);
    mx[3] = fmaxf(mx[3], xv.w);
    if (sel) {
      tk[0] += xv.x; tk[1] += xv.y; tk[2] += xv.z; tk[3] += xv.w;
    }
  }
  float* po = pooled + (size_t)b * 1024;
  const float invn = 1.f / (float)(n > 0 ? n : 1);
  const float invk = (k > 0) ? 1.f / (float)k : 0.f;
  // mean
  *reinterpret_cast<float4*>(&r4[sub][fq * 4]) = make_float4(mean[0], mean[1], mean[2], mean[3]);
  __syncthreads();
  if (t < 256) {
    float tot = 0.f;
#pragma unroll
    for (int q = 0; q < 8; ++q) tot += r4[q][t];
    po[t] = tot * invn;
  }
  __syncthreads();
  // attn
  *reinterpret_cast<float4*>(&r4[sub][fq * 4]) = make_float4(attn[0], attn[1], attn[2], attn[3]);
  __syncthreads();
  if (t < 256) {
    float tot = 0.f;
#pragma unroll
    for (int q = 0; q < 8; ++q) tot += r4[q][t];
    po[256 + t] = tot * inv_denom;
  }
  __syncthreads();
  // max
  *reinterpret_cast<float4*>(&r4[sub][fq * 4]) = make_float4(mx[0], mx[1], mx[2], mx[3]);
  __syncthreads();
  if (t < 256) {
    float tot = -INFINITY;
#pragma unroll
    for (int q = 0; q < 8; ++q) tot = fmaxf(tot, r4[q][t]);
    po[512 + t] = (n > 0) ? tot : 0.f;
  }
  __syncthreads();
  // topk
  *reinterpret_cast<float4*>(&r4[sub][fq * 4]) = make_float4(tk[0], tk[1], tk[2], tk[3]);
  __syncthreads();
  if (t < 256) {
    float tot = 0.f;
#pragma unroll
    for (int q = 0; q < 8; ++q) tot += r4[q][t];
    po[768 + t] = tot * invk;
  }
}

// ---------------- K5: final GEMM [512,1024]@[1024,256], split-K=8 ----------------
__global__ __launch_bounds__(256) void k_gemm(const float* __restrict__ pooled,
                                              const float* __restrict__ Wf,
                                              float* __restrict__ gacc) {
  const int t = threadIdx.x;
  const int r0 = blockIdx.x * 8;
  const int kc0 = blockIdx.y * 128;
  __shared__ float ps[8][132];
  {
    const int r = t >> 5;
    const int c = (t & 31) << 2;
    *reinterpret_cast<float4*>(&ps[r][c]) =
        *reinterpret_cast<const float4*>(pooled + (size_t)(r0 + r) * 1024 + kc0 + c);
  }
  __syncthreads();
  float acc[8];
#pragma unroll
  for (int r = 0; r < 8; ++r) acc[r] = 0.f;
#pragma unroll 4
  for (int c = 0; c < 128; ++c) {
    const float wf = Wf[(size_t)(kc0 + c) * 256 + t];
#pragma unroll
    for (int r = 0; r < 8; ++r) acc[r] = fmaf(ps[r][c], wf, acc[r]);
  }
  float* go = gacc + ((size_t)blockIdx.y * B_GRAPHS + r0) * 256;
#pragma unroll
  for (int r = 0; r < 8; ++r) go[r * 256 + t] = acc[r];
}

// ---------------- K6: reduce split-K + bias + relu -> out ----------------
__global__ __launch_bounds__(256) void k_out(const float* __restrict__ gacc,
                                             const float* __restrict__ bf,
                                             float* __restrict__ out) {
  const int i = blockIdx.x * 256 + threadIdx.x;
  float v = bf[i & 255];
#pragma unroll
  for (int ks = 0; ks < 8; ++ks) v += gacc[(size_t)ks * (B_GRAPHS * 256) + i];
  out[i] = fmaxf(v, 0.f);
}

extern "C" void kernel_launch(void* const* d_in, const int* in_sizes, int n_in,
                              void* d_out, int out_size, void* d_ws, size_t ws_size,
                              hipStream_t stream) {
  const float* x  = (const float*)d_in[0];
  const int* batch = (const int*)d_in[1];
  const float* W1 = (const float*)d_in[2];
  const float* b1 = (const float*)d_in[3];
  const float* W2 = (const float*)d_in[4];
  const float* b2 = (const float*)d_in[5];
  const float* Wf = (const float*)d_in[6];
  const float* bf = (const float*)d_in[7];
  const int N = in_sizes[1];     // 131072
  const int B = B_GRAPHS;

  // ws floats: s[N] | seg_start[1024 ints] | pooled[B*1024] | gacc[8*B*256] | W1s[3*128*256 u16]
  float* ws = (float*)d_ws;
  float* s = ws;
  int* seg_start = (int*)(ws + N);
  float* pooled = ws + N + 1024;
  float* gacc = pooled + (size_t)B * 1024;
  ushort* W1s = (ushort*)(gacc + (size_t)8 * B * 256);

  k_prep_w1<<<dim3(128), dim3(256), 0, stream>>>(W1, W1s);
  k_seg_bounds<<<dim3((B + 1 + 255) / 256), dim3(256), 0, stream>>>(batch, seg_start, N, B);
  k_score_mfma<<<dim3(N / 128), dim3(256), 0, stream>>>(x, W1s, b1, W2, b2, s);
  k_pool_fused<<<dim3(B), dim3(512), 0, stream>>>(x, s, seg_start, pooled);
  k_gemm<<<dim3(B / 8, 8), dim3(256), 0, stream>>>(pooled, Wf, gacc);
  k_out<<<dim3((B * 256) / 256), dim3(256), 0, stream>>>(gacc, bf, (float*)d_out);
}

// Round 4
// 119.488 us; speedup vs baseline: 1.2490x; 1.2490x over previous
//
#include <hip/hip_runtime.h>
#include <math.h>

#define N_NODES 131072
#define H 256
#define HH 128
#define B_GRAPHS 512

typedef __attribute__((ext_vector_type(8))) short bfrag8;
typedef __attribute__((ext_vector_type(16))) float f32x16;

__device__ __forceinline__ float bfhi(float v) {
  return __builtin_bit_cast(float, __builtin_bit_cast(unsigned, v) & 0xFFFF0000u);
}

// ---------------- K0: pre-split W1 into 3 bf16 planes, FRAGMENT-MAJOR ----------------
// W1f[s][ks][g][col][e] : k = ks*16 + g*8 + e  (s=split plane 0..2, ks=substep 0..15)
// flat index = (((s*16 + ks)*2 + g)*128 + col)*8 + e
__global__ void k_prep_w1(const float* __restrict__ W1, ushort* __restrict__ W1f) {
  const int idx = blockIdx.x * 256 + threadIdx.x;  // 32768 = 256*128
  const int k = idx >> 7, c = idx & 127;
  const float v = W1[idx];  // W1 is [256][128] row-major: W1[k*128+c]
  const float r = v - bfhi(v);
  const float r2 = r - bfhi(r);
  const int ks = k >> 4, g = (k >> 3) & 1, e = k & 7;
  const int base = (((ks)*2 + g) * 128 + c) * 8 + e;
  const int plane = 16 * 2 * 128 * 8;  // 32768
  W1f[0 * plane + base] = (ushort)(__builtin_bit_cast(unsigned, v) >> 16);
  W1f[1 * plane + base] = (ushort)(__builtin_bit_cast(unsigned, r) >> 16);
  W1f[2 * plane + base] = (ushort)(__builtin_bit_cast(unsigned, r2) >> 16);
}

// ---------------- K1: segment bounds (batch is sorted) ----------------
__global__ void k_seg_bounds(const int* __restrict__ batch, int* __restrict__ seg_start,
                             int N, int B) {
  int b = blockIdx.x * blockDim.x + threadIdx.x;
  if (b > B) return;
  int lo = 0, hi = N;
  while (lo < hi) {
    int mid = (lo + hi) >> 1;
    if (batch[mid] < b) lo = mid + 1; else hi = mid;
  }
  seg_start[b] = lo;
}

// ---------------- K2: score MLP via split-bf16 MFMA ----------------
// 128x128 tile, 4 waves 2x2, LDS = raw fp32 x-tile [128][32], XOR-swizzled 16B chunks,
// double-buffered, ONE barrier per K-iter. B frags direct from L2 (fragment-major W1f).
#define PROD(sa, sb)                                                                        \
  do {                                                                                      \
    acc[0][0] = __builtin_amdgcn_mfma_f32_32x32x16_bf16(af[sa][0], bb[sub][sb][0],          \
                                                        acc[0][0], 0, 0, 0);                \
    acc[0][1] = __builtin_amdgcn_mfma_f32_32x32x16_bf16(af[sa][0], bb[sub][sb][1],          \
                                                        acc[0][1], 0, 0, 0);                \
    acc[1][0] = __builtin_amdgcn_mfma_f32_32x32x16_bf16(af[sa][1], bb[sub][sb][0],          \
                                                        acc[1][0], 0, 0, 0);                \
    acc[1][1] = __builtin_amdgcn_mfma_f32_32x32x16_bf16(af[sa][1], bb[sub][sb][1],          \
                                                        acc[1][1], 0, 0, 0);                \
  } while (0)

__device__ __forceinline__ void split8(const float4 v0, const float4 v1,
                                       bfrag8& p1, bfrag8& p2, bfrag8& p3) {
  const float vals[8] = {v0.x, v0.y, v0.z, v0.w, v1.x, v1.y, v1.z, v1.w};
#pragma unroll
  for (int e = 0; e < 8; ++e) {
    const float v = vals[e];
    const float r = v - bfhi(v);
    const float r2 = r - bfhi(r);
    p1[e] = (short)(__builtin_bit_cast(unsigned, v) >> 16);
    p2[e] = (short)(__builtin_bit_cast(unsigned, r) >> 16);
    p3[e] = (short)(__builtin_bit_cast(unsigned, r2) >> 16);
  }
}

__global__ __launch_bounds__(256, 3) void k_score_mfma(
    const float* __restrict__ x, const ushort* __restrict__ W1f,
    const float* __restrict__ b1, const float* __restrict__ W2,
    const float* __restrict__ b2, float* __restrict__ s_out) {
  __shared__ float smem[8192];  // 32 KB: dbuf [2][128][32]; epilogue reuses as part[128*64]
  const int t = threadIdx.x;
  const int lane = t & 63;
  const int w = t >> 6;
  const int wr = w >> 1, wc = w & 1;
  const int nl = lane & 31, g = lane >> 5;
  const int node0 = blockIdx.x * 128;

  // staging map: thread t -> rows q*32+srow (q=0..3), 16B chunk schunk of the 128B k-slice
  const int srow = t >> 3, schunk = t & 7;
  const int swz = (schunk ^ (srow & 7)) << 2;  // swizzled chunk -> float offset

  const f32x16 zero = (f32x16)0.0f;
  f32x16 acc[2][2];
  acc[0][0] = zero; acc[0][1] = zero; acc[1][0] = zero; acc[1][1] = zero;

  // prologue: stage tile 0 into buf0
#pragma unroll
  for (int q = 0; q < 4; ++q) {
    const float4 v = *(const float4*)(x + (size_t)(node0 + q * 32 + srow) * H + schunk * 4);
    *(float4*)&smem[(q * 32 + srow) * 32 + swz] = v;
  }
  __syncthreads();

#pragma unroll
  for (int it = 0; it < 8; ++it) {
    const int kc = it * 32;
    const int cur = it & 1;
    // prefetch next x tile into regs (issue-early)
    float4 gx[4];
    if (it < 7) {
#pragma unroll
      for (int q = 0; q < 4; ++q)
        gx[q] = *(const float4*)(x + (size_t)(node0 + q * 32 + srow) * H + kc + 32 + schunk * 4);
    }
    // load B frags for this iter (both substeps) from L2-hot W1f, fully coalesced
    bfrag8 bb[2][3][2];
#pragma unroll
    for (int sub = 0; sub < 2; ++sub)
#pragma unroll
      for (int s = 0; s < 3; ++s)
#pragma unroll
        for (int j = 0; j < 2; ++j) {
          const int ks = it * 2 + sub;
          bb[sub][s][j] = *(const bfrag8*)(W1f + (size_t)(((s * 16 + ks) * 2 + g) * 128 +
                                                          (wc * 64 + j * 32 + nl)) * 8);
        }
    // compute both substeps from swizzled LDS
#pragma unroll
    for (int sub = 0; sub < 2; ++sub) {
      const int k0 = sub * 16;
      bfrag8 af[3][2];
#pragma unroll
      for (int i = 0; i < 2; ++i) {
        const int R = wr * 64 + i * 32 + nl;
        const int c0 = (k0 >> 2) + g * 2;
        const float4 v0 = *(const float4*)&smem[cur * 4096 + R * 32 + ((c0 ^ (R & 7)) << 2)];
        const float4 v1 =
            *(const float4*)&smem[cur * 4096 + R * 32 + (((c0 + 1) ^ (R & 7)) << 2)];
        split8(v0, v1, af[0][i], af[1][i], af[2][i]);
      }
      PROD(0, 0); PROD(1, 0); PROD(0, 1); PROD(1, 1); PROD(2, 0); PROD(0, 2);
    }
    // write-late: staged tile t+1 into the other buffer
    if (it < 7) {
#pragma unroll
      for (int q = 0; q < 4; ++q)
        *(float4*)&smem[(cur ^ 1) * 4096 + (q * 32 + srow) * 32 + swz] = gx[q];
    }
    __syncthreads();
  }

  // ---- epilogue: layer 2 in fp32 (proven R2 mapping) ----
  float* part = smem;  // [128][64]
  const int col0 = wc * 64 + nl;
  const float b1v0 = b1[col0], b1v1 = b1[col0 + 32];
  const float w2v0 = W2[col0], w2v1 = W2[col0 + 32];
#pragma unroll
  for (int i = 0; i < 2; ++i) {
#pragma unroll
    for (int r = 0; r < 16; ++r) {
      const int nodeL = wr * 64 + i * 32 + (r & 3) + 8 * (r >> 2) + 4 * g;
      const float h0 = acc[i][0][r] + b1v0;
      const float h1 = acc[i][1][r] + b1v1;
      const float p = fmaxf(h0, 0.f) * w2v0 + fmaxf(h1, 0.f) * w2v1;
      part[nodeL * 64 + wc * 32 + nl] = p;
    }
  }
  __syncthreads();
  if (t < 128) {
    float sv = b2[0];
#pragma unroll 8
    for (int cc = 0; cc < 64; ++cc) {
      const int c2 = (cc + t) & 63;
      sv += part[t * 64 + c2];
    }
    s_out[node0 + t] = sv;
  }
}

// ---------------- K3: fused softmax stats + top-k select + single-pass pools ----------------
__global__ __launch_bounds__(512) void k_pool_fused(const float* __restrict__ x,
                                                    const float* __restrict__ s,
                                                    const int* __restrict__ seg_start,
                                                    float* __restrict__ pooled) {
  const int b = blockIdx.x;
  const int t = threadIdx.x;
  const int start = seg_start[b];
  const int end = seg_start[b + 1];
  const int n = end - start;

  __shared__ float s_lds[1024];
  __shared__ float red[512];
  __shared__ float thr_sh;
  __shared__ int thri_sh;
  __shared__ float r4[8][264];

  const bool fits = (n <= 1024);
  if (fits) {
    for (int i = t; i < n; i += 512) s_lds[i] = s[start + i];
  }
  __syncthreads();
  const float* sseg = fits ? s_lds : (s + start);

  float m = -INFINITY;
  for (int i = t; i < n; i += 512) m = fmaxf(m, sseg[i]);
  red[t] = m;
  __syncthreads();
  for (int off = 256; off > 0; off >>= 1) {
    if (t < off) red[t] = fmaxf(red[t], red[t + off]);
    __syncthreads();
  }
  const float smax = red[0];
  __syncthreads();
  float d = 0.f;
  for (int i = t; i < n; i += 512) d += __expf(sseg[i] - smax);
  red[t] = d;
  __syncthreads();
  for (int off = 256; off > 0; off >>= 1) {
    if (t < off) red[t] += red[t + off];
    __syncthreads();
  }
  const float denom = red[0];
  __syncthreads();
  const float inv_denom = (denom > 0.f) ? 1.f / denom : 0.f;

  int k = 0;
  if (n > 0) {
    k = (int)ceilf(0.05f * (float)n);
    if (k < 5) k = 5;
    if (k > 64) k = 64;
    if (k > n) k = n;
  }

  if (t < 64) {
    float pk = INFINITY;
    int pidx = -1;
    for (int r = 0; r < k; ++r) {
      float bk = -INFINITY;
      int bi = 0x7fffffff;
      for (int i = t; i < n; i += 64) {
        const float si = sseg[i];
        const int gi = start + i;
        const bool below = (si < pk) || (si == pk && gi > pidx);
        if (below && (si > bk || (si == bk && gi < bi))) { bk = si; bi = gi; }
      }
#pragma unroll
      for (int off = 32; off > 0; off >>= 1) {
        const float ok = __shfl_xor(bk, off);
        const int oi = __shfl_xor(bi, off);
        if (ok > bk || (ok == bk && oi < bi)) { bk = ok; bi = oi; }
      }
      pk = bk;
      pidx = bi;
    }
    if (t == 0) {
      thr_sh = (k > 0) ? pk : INFINITY;
      thri_sh = (k > 0) ? pidx : -1;
    }
  }
  __syncthreads();
  const float thr = thr_sh;
  const int thri = thri_sh;

  const int fq = t & 63;
  const int sub = t >> 6;
  float mean[4] = {0.f, 0.f, 0.f, 0.f};
  float attn[4] = {0.f, 0.f, 0.f, 0.f};
  float tk[4] = {0.f, 0.f, 0.f, 0.f};
  float mx[4] = {-INFINITY, -INFINITY, -INFINITY, -INFINITY};
  for (int i = sub; i < n; i += 8) {
    const float si = sseg[i];
    const float wi = __expf(si - smax);
    const int gi = start + i;
    const bool sel = (si > thr) || (si == thr && gi <= thri);
    const float4 xv = *reinterpret_cast<const float4*>(x + (size_t)gi * H + fq * 4);
    mean[0] += xv.x; mean[1] += xv.y; mean[2] += xv.z; mean[3] += xv.w;
    attn[0] = fmaf(xv.x, wi, attn[0]);
    attn[1] = fmaf(xv.y, wi, attn[1]);
    attn[2] = fmaf(xv.z, wi, attn[2]);
    attn[3] = fmaf(xv.w, wi, attn[3]);
    mx[0] = fmaxf(mx[0], xv.x);
    mx[1] = fmaxf(mx[1], xv.y);
    mx[2] = fmaxf(mx[2], xv.z);
    mx[3] = fmaxf(mx[3], xv.w);
    if (sel) {
      tk[0] += xv.x; tk[1] += xv.y; tk[2] += xv.z; tk[3] += xv.w;
    }
  }
  float* po = pooled + (size_t)b * 1024;
  const float invn = 1.f / (float)(n > 0 ? n : 1);
  const float invk = (k > 0) ? 1.f / (float)k : 0.f;
  *reinterpret_cast<float4*>(&r4[sub][fq * 4]) = make_float4(mean[0], mean[1], mean[2], mean[3]);
  __syncthreads();
  if (t < 256) {
    float tot = 0.f;
#pragma unroll
    for (int q = 0; q < 8; ++q) tot += r4[q][t];
    po[t] = tot * invn;
  }
  __syncthreads();
  *reinterpret_cast<float4*>(&r4[sub][fq * 4]) = make_float4(attn[0], attn[1], attn[2], attn[3]);
  __syncthreads();
  if (t < 256) {
    float tot = 0.f;
#pragma unroll
    for (int q = 0; q < 8; ++q) tot += r4[q][t];
    po[256 + t] = tot * inv_denom;
  }
  __syncthreads();
  *reinterpret_cast<float4*>(&r4[sub][fq * 4]) = make_float4(mx[0], mx[1], mx[2], mx[3]);
  __syncthreads();
  if (t < 256) {
    float tot = -INFINITY;
#pragma unroll
    for (int q = 0; q < 8; ++q) tot = fmaxf(tot, r4[q][t]);
    po[512 + t] = (n > 0) ? tot : 0.f;
  }
  __syncthreads();
  *reinterpret_cast<float4*>(&r4[sub][fq * 4]) = make_float4(tk[0], tk[1], tk[2], tk[3]);
  __syncthreads();
  if (t < 256) {
    float tot = 0.f;
#pragma unroll
    for (int q = 0; q < 8; ++q) tot += r4[q][t];
    po[768 + t] = tot * invk;
  }
}

// ---------------- K5: final GEMM [512,1024]@[1024,256], split-K=8 ----------------
__global__ __launch_bounds__(256) void k_gemm(const float* __restrict__ pooled,
                                              const float* __restrict__ Wf,
                                              float* __restrict__ gacc) {
  const int t = threadIdx.x;
  const int r0 = blockIdx.x * 8;
  const int kc0 = blockIdx.y * 128;
  __shared__ float ps[8][132];
  {
    const int r = t >> 5;
    const int c = (t & 31) << 2;
    *reinterpret_cast<float4*>(&ps[r][c]) =
        *reinterpret_cast<const float4*>(pooled + (size_t)(r0 + r) * 1024 + kc0 + c);
  }
  __syncthreads();
  float acc[8];
#pragma unroll
  for (int r = 0; r < 8; ++r) acc[r] = 0.f;
#pragma unroll 4
  for (int c = 0; c < 128; ++c) {
    const float wf = Wf[(size_t)(kc0 + c) * 256 + t];
#pragma unroll
    for (int r = 0; r < 8; ++r) acc[r] = fmaf(ps[r][c], wf, acc[r]);
  }
  float* go = gacc + ((size_t)blockIdx.y * B_GRAPHS + r0) * 256;
#pragma unroll
  for (int r = 0; r < 8; ++r) go[r * 256 + t] = acc[r];
}

// ---------------- K6: reduce split-K + bias + relu -> out ----------------
__global__ __launch_bounds__(256) void k_out(const float* __restrict__ gacc,
                                             const float* __restrict__ bf,
                                             float* __restrict__ out) {
  const int i = blockIdx.x * 256 + threadIdx.x;
  float v = bf[i & 255];
#pragma unroll
  for (int ks = 0; ks < 8; ++ks) v += gacc[(size_t)ks * (B_GRAPHS * 256) + i];
  out[i] = fmaxf(v, 0.f);
}

extern "C" void kernel_launch(void* const* d_in, const int* in_sizes, int n_in,
                              void* d_out, int out_size, void* d_ws, size_t ws_size,
                              hipStream_t stream) {
  const float* x  = (const float*)d_in[0];
  const int* batch = (const int*)d_in[1];
  const float* W1 = (const float*)d_in[2];
  const float* b1 = (const float*)d_in[3];
  const float* W2 = (const float*)d_in[4];
  const float* b2 = (const float*)d_in[5];
  const float* Wf = (const float*)d_in[6];
  const float* bf = (const float*)d_in[7];
  const int N = in_sizes[1];     // 131072
  const int B = B_GRAPHS;

  // ws floats: s[N] | seg_start[1024 ints] | pooled[B*1024] | gacc[8*B*256] | W1f[3*32768 u16]
  float* ws = (float*)d_ws;
  float* s = ws;
  int* seg_start = (int*)(ws + N);
  float* pooled = ws + N + 1024;
  float* gacc = pooled + (size_t)B * 1024;
  ushort* W1f = (ushort*)(gacc + (size_t)8 * B * 256);

  k_prep_w1<<<dim3(128), dim3(256), 0, stream>>>(W1, W1f);
  k_seg_bounds<<<dim3((B + 1 + 255) / 256), dim3(256), 0, stream>>>(batch, seg_start, N, B);
  k_score_mfma<<<dim3(N / 128), dim3(256), 0, stream>>>(x, W1f, b1, W2, b2, s);
  k_pool_fused<<<dim3(B), dim3(512), 0, stream>>>(x, s, seg_start, pooled);
  k_gemm<<<dim3(B / 8, 8), dim3(256), 0, stream>>>(pooled, Wf, gacc);
  k_out<<<dim3((B * 256) / 256), dim3(256), 0, stream>>>(gacc, bf, (float*)d_out);
}